// Round 8
// baseline (292.091 us; speedup 1.0000x reference)
//
#include <hip/hip_runtime.h>
#include <cstdint>
#include <cstddef>

typedef unsigned short u16;
typedef unsigned int   u32;
typedef __attribute__((ext_vector_type(8))) short bf16x8;
typedef __attribute__((ext_vector_type(4))) float f32x4;

#define D_IN  256
#define D_H   128
#define D_OUT 64
#define LSTR  72   // LDS row stride in u16 (144 B = 9*16 B: keeps b128 alignment, non-pow2)

__device__ __forceinline__ float bf2f(u16 u){
  union { u32 i; float f; } v; v.i = ((u32)u) << 16; return v.f;
}
__device__ __forceinline__ u16 f2bf(float f){
  union { float f; u32 i; } v; v.f = f;
  u32 r = (v.i + 0x7fffu + ((v.i >> 16) & 1u)) >> 16;
  return (u16)r;
}

// ---------------- weight prep + deg zero (fused) ----------------
__global__ void k_wprep(const float* __restrict__ W0, const float* __restrict__ W1,
                        u16* __restrict__ W0t, u16* __restrict__ W1t,
                        int* __restrict__ deg, int n_t){
  int i = blockIdx.x * 256 + threadIdx.x;
  if (i < 128 * 256){
    int n = i >> 8, k = i & 255;
    W0t[i] = f2bf(W0[(size_t)k * 128 + n]);
  } else if (i < 128 * 256 + 64 * 128){
    int j = i - 128 * 256;
    int n = j >> 7, k = j & 127;
    W1t[j] = f2bf(W1[(size_t)k * 64 + n]);
  } else if (i - (128 * 256 + 64 * 128) < n_t){
    deg[i - (128 * 256 + 64 * 128)] = 0;
  }
}

// ---------------- graph prep ----------------
__global__ void k_deg(const int* __restrict__ dst, int E, int* __restrict__ deg){
  int e = blockIdx.x * 256 + threadIdx.x;
  if (e < E) atomicAdd(&deg[dst[e]], 1);
}

__global__ __launch_bounds__(256) void k_bsum(const int* __restrict__ deg, int N,
                                              int* __restrict__ bsum){
  __shared__ int s[256];
  int tid = threadIdx.x;
  int i = blockIdx.x * 256 + tid;
  s[tid] = (i < N) ? deg[i] : 0;
  __syncthreads();
  for (int o = 128; o > 0; o >>= 1){
    if (tid < o) s[tid] += s[tid + o];
    __syncthreads();
  }
  if (tid == 0) bsum[blockIdx.x] = s[0];
}

__global__ __launch_bounds__(256) void k_bscan(int* __restrict__ bsum, int nb){
  __shared__ int s[256];
  int tid = threadIdx.x;
  int v = (tid < nb) ? bsum[tid] : 0;
  s[tid] = v;
  __syncthreads();
  for (int o = 1; o < 256; o <<= 1){
    int t = (tid >= o) ? s[tid - o] : 0;
    __syncthreads();
    s[tid] += t;
    __syncthreads();
  }
  if (tid < nb) bsum[tid] = s[tid] - v;
}

__global__ __launch_bounds__(256) void k_off(const int* __restrict__ deg, int N,
                                             const int* __restrict__ bsum,
                                             int* __restrict__ off, int* __restrict__ cursor,
                                             float* __restrict__ dinv){
  __shared__ int s[256];
  int tid = threadIdx.x;
  int i = blockIdx.x * 256 + tid;
  int v = (i < N) ? deg[i] : 0;
  s[tid] = v;
  __syncthreads();
  for (int o = 1; o < 256; o <<= 1){
    int t = (tid >= o) ? s[tid - o] : 0;
    __syncthreads();
    s[tid] += t;
    __syncthreads();
  }
  if (i < N){
    int excl = s[tid] - v + bsum[blockIdx.x];
    off[i] = excl;
    cursor[i] = excl;
    dinv[i] = rsqrtf((float)v + 1.0f);
  }
}

__global__ void k_fill(const int* __restrict__ src, const int* __restrict__ dst,
                       int E, int* __restrict__ cursor, int* __restrict__ csr){
  int e = blockIdx.x * 256 + threadIdx.x;
  if (e < E){
    int d = dst[e];
    int p = atomicAdd(&cursor[d], 1);
    csr[p] = src[e];
  }
}

// ---------------- GEMM1 (MFMA, BM=64, sw-pipelined): X f32 @ W0t -> h1 bf16 ----------------
// Tile 64x128, BK=64; 4 waves in 2x2, each 32x64 (2x4 mfma_16x16x32).
__global__ __launch_bounds__(256) void k_gemm1(
    const float* __restrict__ Xs, const float* __restrict__ Xt,
    const u16* __restrict__ W0t, int M, int n_s,
    u16* __restrict__ out)
{
  __shared__ u16 As[64 * LSTR];
  __shared__ u16 Bs[128 * LSTR];
  const int t    = threadIdx.x;
  const int wave = t >> 6, lane = t & 63;
  const int wm   = (wave >> 1) * 32, wn = (wave & 1) * 64;
  const int lm   = lane & 15, quad = lane >> 4;
  const int row0 = blockIdx.x * 64;

  f32x4 acc[2][4];
  const f32x4 z = {0.f, 0.f, 0.f, 0.f};
  #pragma unroll
  for (int i = 0; i < 2; i++)
    #pragma unroll
    for (int j = 0; j < 4; j++) acc[i][j] = z;

  // A staging: thread t -> row ar (0..63), k-quarter kq (16 f32)
  const int ar = t >> 2;
  const int kq = (t & 3) * 16;
  const int r  = row0 + ar;
  const float* xp = nullptr;
  if (r < M) xp = (r < n_s) ? (Xs + (size_t)r * D_IN) : (Xt + (size_t)(r - n_s) * D_IN);
  // B staging: thread t -> n-row bn (0..127), k-half bk (32 u16)
  const int bn = t >> 1;
  const int bk = (t & 1) * 32;
  const u16* wrow = W0t + (size_t)bn * D_IN + bk;

  float4 a4[4];
  int4   b4[4];
  if (xp){
    #pragma unroll
    for (int j = 0; j < 4; j++) a4[j] = *(const float4*)(xp + kq + j * 4);
  } else {
    float4 zz = make_float4(0,0,0,0);
    #pragma unroll
    for (int j = 0; j < 4; j++) a4[j] = zz;
  }
  #pragma unroll
  for (int j = 0; j < 4; j++) b4[j] = *(const int4*)(wrow + j * 8);

  for (int k0 = 0; k0 < D_IN; k0 += 64){
    __syncthreads();
    {
      u16 abuf[16];
      #pragma unroll
      for (int j = 0; j < 4; j++){
        abuf[j*4+0] = f2bf(a4[j].x); abuf[j*4+1] = f2bf(a4[j].y);
        abuf[j*4+2] = f2bf(a4[j].z); abuf[j*4+3] = f2bf(a4[j].w);
      }
      u16* ap = &As[ar * LSTR + kq];
      *(int4*)(ap + 0) = *(int4*)&abuf[0];
      *(int4*)(ap + 8) = *(int4*)&abuf[8];
      u16* bp = &Bs[bn * LSTR + bk];
      *(int4*)(bp +  0) = b4[0];
      *(int4*)(bp +  8) = b4[1];
      *(int4*)(bp + 16) = b4[2];
      *(int4*)(bp + 24) = b4[3];
    }
    __syncthreads();

    if (k0 + 64 < D_IN){
      if (xp){
        #pragma unroll
        for (int j = 0; j < 4; j++) a4[j] = *(const float4*)(xp + k0 + 64 + kq + j * 4);
      }
      #pragma unroll
      for (int j = 0; j < 4; j++) b4[j] = *(const int4*)(wrow + k0 + 64 + j * 8);
    }

    #pragma unroll
    for (int kk = 0; kk < 64; kk += 32){
      bf16x8 af[2], bfr[4];
      #pragma unroll
      for (int i = 0; i < 2; i++)
        af[i] = *(const bf16x8*)&As[(wm + i*16 + lm) * LSTR + kk + quad*8];
      #pragma unroll
      for (int i = 0; i < 4; i++)
        bfr[i] = *(const bf16x8*)&Bs[(wn + i*16 + lm) * LSTR + kk + quad*8];
      #pragma unroll
      for (int mi = 0; mi < 2; mi++)
        #pragma unroll
        for (int ni = 0; ni < 4; ni++)
          acc[mi][ni] = __builtin_amdgcn_mfma_f32_16x16x32_bf16(
              af[mi], bfr[ni], acc[mi][ni], 0, 0, 0);
    }
  }

  #pragma unroll
  for (int mi = 0; mi < 2; mi++){
    int rbase = row0 + wm + mi * 16 + quad * 4;
    #pragma unroll
    for (int rr = 0; rr < 4; rr++){
      int m = rbase + rr;
      if (m >= M) continue;
      u16* op = out + (size_t)m * D_H + wn + lm;
      #pragma unroll
      for (int ni = 0; ni < 4; ni++)
        op[ni * 16] = f2bf(acc[mi][ni][rr]);
    }
  }
}

// ---------------- fused aggregation (wide gather): one wave per dst node ----------------
// lane = g*16 + c: subgroup g handles edge i+g, chunk c covers feats c*8..c*8+7 (int4).
// s_raw/s_rel accumulated per lane; xor-shuffle reduce over subgroups; in-place u_t.
__global__ __launch_bounds__(256) void k_aggf(
    const int* __restrict__ off, const int* __restrict__ deg,
    const int* __restrict__ csr, const float* __restrict__ dinv,
    u16* __restrict__ h1, int n_s, int n_t)
{
  int w    = (blockIdx.x * 256 + threadIdx.x) >> 6;
  int lane = threadIdx.x & 63;
  if (w >= n_t) return;
  const int g = lane >> 4;
  const int c = lane & 15;
  int start = off[w];
  int n     = deg[w];

  float r[8], p[8];
  #pragma unroll
  for (int q = 0; q < 8; q++){ r[q] = 0.f; p[q] = 0.f; }

  int i = 0;
  for (; i + 8 <= n; i += 8){
    int sa = csr[start + i + g];
    int sb = csr[start + i + 4 + g];
    int4 da = *(const int4*)(h1 + (size_t)sa * D_H + c * 8);
    int4 db = *(const int4*)(h1 + (size_t)sb * D_H + c * 8);
    const u16* ha = (const u16*)&da;
    const u16* hb = (const u16*)&db;
    #pragma unroll
    for (int q = 0; q < 8; q++){
      float va = bf2f(ha[q]), vb = bf2f(hb[q]);
      r[q] += va + vb;
      p[q] += fmaxf(va, 0.f) + fmaxf(vb, 0.f);
    }
  }
  for (; i < n; i += 4){
    if (i + g < n){
      int sa = csr[start + i + g];
      int4 da = *(const int4*)(h1 + (size_t)sa * D_H + c * 8);
      const u16* ha = (const u16*)&da;
      #pragma unroll
      for (int q = 0; q < 8; q++){
        float va = bf2f(ha[q]);
        r[q] += va;
        p[q] += fmaxf(va, 0.f);
      }
    }
  }

  // reduce across the 4 subgroups (lanes c, c+16, c+32, c+48)
  #pragma unroll
  for (int q = 0; q < 8; q++){
    r[q] += __shfl_xor(r[q], 16, 64);
    r[q] += __shfl_xor(r[q], 32, 64);
    p[q] += __shfl_xor(p[q], 16, 64);
    p[q] += __shfl_xor(p[q], 32, 64);
  }

  if (g == 0){
    float di  = dinv[w];
    float di2 = di * di;
    u16* selfp = h1 + (size_t)(n_s + w) * D_H + c * 8;
    int4 hs = *(const int4*)selfp;
    const u16* hh = (const u16*)&hs;
    u16 ob[8];
    #pragma unroll
    for (int q = 0; q < 8; q++){
      float zq = fmaxf(di * r[q] + di2 * bf2f(hh[q]), 0.f);
      float uq = di * p[q] + di2 * zq;
      ob[q] = f2bf(uq);
    }
    *(int4*)selfp = *(int4*)ob;
  }
}

// ---------------- GEMM2 (MFMA, BM=64, sw-pipelined): A @ W1t -> d_out f32 ----------------
// Tile 64x64, BK=64, K=128; 4 waves stacked in m, each 16x64 (1x4 mfma).
// A row r<n_s: relu on load; r>=n_s: raw u_t.
__global__ __launch_bounds__(256) void k_gemm2(
    const u16* __restrict__ h1, const u16* __restrict__ W1t,
    int M, int n_s, float* __restrict__ out)
{
  __shared__ u16 As[64 * LSTR];
  __shared__ u16 Bs[64 * LSTR];
  const int t    = threadIdx.x;
  const int wave = t >> 6, lane = t & 63;
  const int wm   = wave * 16;
  const int lm   = lane & 15, quad = lane >> 4;
  const int row0 = blockIdx.x * 64;

  f32x4 acc[4];
  const f32x4 z = {0.f, 0.f, 0.f, 0.f};
  #pragma unroll
  for (int j = 0; j < 4; j++) acc[j] = z;

  // A staging: row ar (0..63), k-quarter kq (16 u16)
  const int ar = t >> 2;
  const int kq = (t & 3) * 16;
  const int r  = row0 + ar;
  const bool relu_a = (r < n_s);
  // B staging: n-row bn (0..63), k-quarter (16 u16)
  const int bn = t >> 2;
  const int bk = (t & 3) * 16;

  int4 a4[2], w4[2];
  if (r < M){
    const u16* hp = h1 + (size_t)r * D_H + kq;
    a4[0] = *(const int4*)(hp);
    a4[1] = *(const int4*)(hp + 8);
  } else {
    a4[0] = make_int4(0,0,0,0); a4[1] = a4[0];
  }
  w4[0] = *(const int4*)(W1t + (size_t)bn * D_H + bk);
  w4[1] = *(const int4*)(W1t + (size_t)bn * D_H + bk + 8);

  for (int k0 = 0; k0 < D_H; k0 += 64){
    __syncthreads();
    {
      u16 abuf[16];
      #pragma unroll
      for (int j = 0; j < 2; j++){
        u16* hh = (u16*)&a4[j];
        #pragma unroll
        for (int q = 0; q < 8; q++){
          u16 v = hh[q];
          abuf[j*8+q] = (relu_a && (v & 0x8000u)) ? (u16)0 : v;
        }
      }
      u16* ap = &As[ar * LSTR + kq];
      *(int4*)(ap + 0) = *(int4*)&abuf[0];
      *(int4*)(ap + 8) = *(int4*)&abuf[8];
      u16* bp = &Bs[bn * LSTR + bk];
      *(int4*)(bp + 0) = w4[0];
      *(int4*)(bp + 8) = w4[1];
    }
    __syncthreads();

    if (k0 + 64 < D_H){
      if (r < M){
        const u16* hp = h1 + (size_t)r * D_H + k0 + 64 + kq;
        a4[0] = *(const int4*)(hp);
        a4[1] = *(const int4*)(hp + 8);
      }
      w4[0] = *(const int4*)(W1t + (size_t)bn * D_H + k0 + 64 + bk);
      w4[1] = *(const int4*)(W1t + (size_t)bn * D_H + k0 + 64 + bk + 8);
    }

    #pragma unroll
    for (int kk = 0; kk < 64; kk += 32){
      bf16x8 af;
      bf16x8 bfr[4];
      af = *(const bf16x8*)&As[(wm + lm) * LSTR + kk + quad*8];
      #pragma unroll
      for (int i = 0; i < 4; i++)
        bfr[i] = *(const bf16x8*)&Bs[(i*16 + lm) * LSTR + kk + quad*8];
      #pragma unroll
      for (int ni = 0; ni < 4; ni++)
        acc[ni] = __builtin_amdgcn_mfma_f32_16x16x32_bf16(
            af, bfr[ni], acc[ni], 0, 0, 0);
    }
  }

  {
    int rbase = row0 + wm + quad * 4;
    #pragma unroll
    for (int rr = 0; rr < 4; rr++){
      int m = rbase + rr;
      if (m >= M) continue;
      float* op = out + (size_t)m * D_OUT + lm;
      #pragma unroll
      for (int ni = 0; ni < 4; ni++)
        op[ni * 16] = acc[ni][rr];
    }
  }
}

static inline size_t alup(size_t x){ return (x + 255) & ~(size_t)255; }

extern "C" void kernel_launch(void* const* d_in, const int* in_sizes, int n_in,
                              void* d_out, int out_size, void* d_ws, size_t ws_size,
                              hipStream_t stream)
{
  const int*   ei = (const int*)d_in[0];
  const float* xs = (const float*)d_in[1];
  const float* xt = (const float*)d_in[2];
  const float* W0 = (const float*)d_in[3];
  const float* W1 = (const float*)d_in[4];
  const int E   = in_sizes[0] / 2;
  const int n_s = in_sizes[1] / D_IN;
  const int n_t = in_sizes[2] / D_IN;
  const int M   = n_s + n_t;
  const int* src = ei;       // edge_index row 0
  const int* dst = ei + E;   // edge_index row 1 (0-based target index)
  const int nb_t = (n_t + 255) / 256;

  // workspace layout (~29 MB)
  char* p = (char*)d_ws;
  int*   deg    = (int*)p;    p += alup((size_t)n_t * 4);
  int*   off    = (int*)p;    p += alup((size_t)n_t * 4);
  int*   cursor = (int*)p;    p += alup((size_t)n_t * 4);
  float* dinv   = (float*)p;  p += alup((size_t)n_t * 4);
  int*   bsum   = (int*)p;    p += alup((size_t)nb_t * 4);
  int*   csr    = (int*)p;    p += alup((size_t)E * 4);
  u16*   W0t    = (u16*)p;    p += alup((size_t)D_H * D_IN * 2);
  u16*   W1t    = (u16*)p;    p += alup((size_t)D_OUT * D_H * 2);
  u16*   h1     = (u16*)p;    p += alup((size_t)M * D_H * 2);

  const int wprep_n = 128*256 + 64*128 + n_t;
  k_wprep <<<(wprep_n + 255) / 256, 256, 0, stream>>>(W0, W1, W0t, W1t, deg, n_t);
  k_deg   <<<(E + 255) / 256, 256, 0, stream>>>(dst, E, deg);
  k_bsum  <<<nb_t, 256, 0, stream>>>(deg, n_t, bsum);
  k_bscan <<<1, 256, 0, stream>>>(bsum, nb_t);
  k_off   <<<nb_t, 256, 0, stream>>>(deg, n_t, bsum, off, cursor, dinv);
  k_fill  <<<(E + 255) / 256, 256, 0, stream>>>(src, dst, E, cursor, csr);

  // layer 1: h1 = X @ W0 (raw, all rows, bf16)
  k_gemm1<<<(M + 63) / 64, 256, 0, stream>>>(xs, xt, W0t, M, n_s, h1);
  // fused agg: h1 target rows <- u_t (single gather pass for both layers)
  k_aggf <<<(n_t + 3) / 4, 256, 0, stream>>>(off, deg, csr, dinv, h1, n_s, n_t);
  // layer 2: d_out = [relu(h1_s); u_t] @ W1  (final output)
  k_gemm2<<<(M + 63) / 64, 256, 0, stream>>>(h1, W1t, M, n_s, (float*)d_out);
}

// Round 9
// 279.191 us; speedup vs baseline: 1.0462x; 1.0462x over previous
//
#include <hip/hip_runtime.h>
#include <cstdint>
#include <cstddef>

typedef unsigned short u16;
typedef unsigned int   u32;
typedef __attribute__((ext_vector_type(8))) short bf16x8;
typedef __attribute__((ext_vector_type(4))) float f32x4;

#define D_IN  256
#define D_H   128
#define D_OUT 64
#define LSTR  72   // LDS row stride in u16: 144 B, keeps 16 B align, non-pow2

__device__ __forceinline__ float bf2f(u16 u){
  union { u32 i; float f; } v; v.i = ((u32)u) << 16; return v.f;
}
__device__ __forceinline__ u16 f2bf(float f){
  union { float f; u32 i; } v; v.f = f;
  u32 r = (v.i + 0x7fffu + ((v.i >> 16) & 1u)) >> 16;
  return (u16)r;
}

// ---------------- weight prep + deg zero (fused) ----------------
__global__ void k_wprep(const float* __restrict__ W0, const float* __restrict__ W1,
                        u16* __restrict__ W0t, u16* __restrict__ W1t,
                        int* __restrict__ deg, int n_t){
  int i = blockIdx.x * 256 + threadIdx.x;
  if (i < 128 * 256){
    int n = i >> 8, k = i & 255;
    W0t[i] = f2bf(W0[(size_t)k * 128 + n]);
  } else if (i < 128 * 256 + 64 * 128){
    int j = i - 128 * 256;
    int n = j >> 7, k = j & 127;
    W1t[j] = f2bf(W1[(size_t)k * 64 + n]);
  } else if (i - (128 * 256 + 64 * 128) < n_t){
    deg[i - (128 * 256 + 64 * 128)] = 0;
  }
}

// ---------------- graph prep ----------------
__global__ void k_deg(const int* __restrict__ dst, int E, int* __restrict__ deg){
  int e = blockIdx.x * 256 + threadIdx.x;
  if (e < E) atomicAdd(&deg[dst[e]], 1);
}

__global__ __launch_bounds__(256) void k_bsum(const int* __restrict__ deg, int N,
                                              int* __restrict__ bsum){
  __shared__ int s[256];
  int tid = threadIdx.x;
  int i = blockIdx.x * 256 + tid;
  s[tid] = (i < N) ? deg[i] : 0;
  __syncthreads();
  for (int o = 128; o > 0; o >>= 1){
    if (tid < o) s[tid] += s[tid + o];
    __syncthreads();
  }
  if (tid == 0) bsum[blockIdx.x] = s[0];
}

// local scan + direct reduction of bsum[0..bid) for the global base (nb <= 256*many, fine)
__global__ __launch_bounds__(256) void k_off(const int* __restrict__ deg, int N,
                                             const int* __restrict__ bsum, int nb,
                                             int* __restrict__ off, int* __restrict__ cursor,
                                             float* __restrict__ dinv){
  __shared__ int s[256];
  __shared__ int sbase[256];
  const int tid = threadIdx.x;
  const int bid = blockIdx.x;
  const int i   = bid * 256 + tid;
  // block base = sum of bsum[j] for j < bid
  int acc = 0;
  for (int j = tid; j < bid; j += 256) acc += bsum[j];
  sbase[tid] = acc;
  int v = (i < N) ? deg[i] : 0;
  s[tid] = v;
  __syncthreads();
  for (int o = 128; o > 0; o >>= 1){
    if (tid < o) sbase[tid] += sbase[tid + o];
    __syncthreads();
  }
  for (int o = 1; o < 256; o <<= 1){
    int t = (tid >= o) ? s[tid - o] : 0;
    __syncthreads();
    s[tid] += t;
    __syncthreads();
  }
  if (i < N){
    int excl = s[tid] - v + sbase[0];
    off[i] = excl;
    cursor[i] = excl;
    dinv[i] = rsqrtf((float)v + 1.0f);
  }
}

__global__ void k_fill(const int* __restrict__ src, const int* __restrict__ dst,
                       int E, int* __restrict__ cursor, int* __restrict__ csr){
  int e = blockIdx.x * 256 + threadIdx.x;
  if (e < E){
    int d = dst[e];
    int p = atomicAdd(&cursor[d], 1);
    csr[p] = src[e];
  }
}

// ---------------- GEMM1 (MFMA, BM=128, sw-pipelined): X f32 @ W0t -> h1 bf16 ----------------
__global__ __launch_bounds__(256) void k_gemm1(
    const float* __restrict__ Xs, const float* __restrict__ Xt,
    const u16* __restrict__ W0t, int M, int n_s,
    u16* __restrict__ out)
{
  __shared__ u16 As[128 * LSTR];
  __shared__ u16 Bs[128 * LSTR];
  const int t    = threadIdx.x;
  const int wave = t >> 6, lane = t & 63;
  const int wm   = (wave >> 1) * 64, wn = (wave & 1) * 64;
  const int lm   = lane & 15, quad = lane >> 4;
  const int row0 = blockIdx.x * 128;

  f32x4 acc[4][4];
  const f32x4 z = {0.f, 0.f, 0.f, 0.f};
  #pragma unroll
  for (int i = 0; i < 4; i++)
    #pragma unroll
    for (int j = 0; j < 4; j++) acc[i][j] = z;

  const int ar = t >> 1;
  const int kh = (t & 1) * 32;
  const int r  = row0 + ar;
  const float* xp = nullptr;
  if (r < M) xp = (r < n_s) ? (Xs + (size_t)r * D_IN) : (Xt + (size_t)(r - n_s) * D_IN);
  const u16* wrow = W0t + (size_t)ar * D_IN + kh;

  float4 a4[8];
  int4   b4[4];
  if (xp){
    #pragma unroll
    for (int j = 0; j < 8; j++) a4[j] = *(const float4*)(xp + kh + j * 4);
  } else {
    float4 zz = make_float4(0,0,0,0);
    #pragma unroll
    for (int j = 0; j < 8; j++) a4[j] = zz;
  }
  #pragma unroll
  for (int j = 0; j < 4; j++) b4[j] = *(const int4*)(wrow + j * 8);

  for (int k0 = 0; k0 < D_IN; k0 += 64){
    __syncthreads();
    {
      u16 abuf[32];
      #pragma unroll
      for (int j = 0; j < 8; j++){
        abuf[j*4+0] = f2bf(a4[j].x); abuf[j*4+1] = f2bf(a4[j].y);
        abuf[j*4+2] = f2bf(a4[j].z); abuf[j*4+3] = f2bf(a4[j].w);
      }
      u16* ap = &As[ar * LSTR + kh];
      *(int4*)(ap +  0) = *(int4*)&abuf[0];
      *(int4*)(ap +  8) = *(int4*)&abuf[8];
      *(int4*)(ap + 16) = *(int4*)&abuf[16];
      *(int4*)(ap + 24) = *(int4*)&abuf[24];
      u16* bp = &Bs[ar * LSTR + kh];
      *(int4*)(bp +  0) = b4[0];
      *(int4*)(bp +  8) = b4[1];
      *(int4*)(bp + 16) = b4[2];
      *(int4*)(bp + 24) = b4[3];
    }
    __syncthreads();

    if (k0 + 64 < D_IN){
      if (xp){
        #pragma unroll
        for (int j = 0; j < 8; j++) a4[j] = *(const float4*)(xp + k0 + 64 + kh + j * 4);
      }
      #pragma unroll
      for (int j = 0; j < 4; j++) b4[j] = *(const int4*)(wrow + k0 + 64 + j * 8);
    }

    #pragma unroll
    for (int kk = 0; kk < 64; kk += 32){
      bf16x8 af[4], bfr[4];
      #pragma unroll
      for (int i = 0; i < 4; i++)
        af[i] = *(const bf16x8*)&As[(wm + i*16 + lm) * LSTR + kk + quad*8];
      #pragma unroll
      for (int i = 0; i < 4; i++)
        bfr[i] = *(const bf16x8*)&Bs[(wn + i*16 + lm) * LSTR + kk + quad*8];
      #pragma unroll
      for (int mi = 0; mi < 4; mi++)
        #pragma unroll
        for (int ni = 0; ni < 4; ni++)
          acc[mi][ni] = __builtin_amdgcn_mfma_f32_16x16x32_bf16(
              af[mi], bfr[ni], acc[mi][ni], 0, 0, 0);
    }
  }

  #pragma unroll
  for (int mi = 0; mi < 4; mi++){
    int rbase = row0 + wm + mi * 16 + quad * 4;
    #pragma unroll
    for (int rr = 0; rr < 4; rr++){
      int m = rbase + rr;
      if (m >= M) continue;
      u16* op = out + (size_t)m * D_H + wn + lm;
      #pragma unroll
      for (int ni = 0; ni < 4; ni++)
        op[ni * 16] = f2bf(acc[mi][ni][rr]);
    }
  }
}

// ---------------- fused aggregation (wide gather): one wave per dst node ----------------
// lane = g*16 + c: subgroup g handles edge i+g, chunk c covers feats c*8..c*8+7 (int4).
__global__ __launch_bounds__(256) void k_aggf(
    const int* __restrict__ off, const int* __restrict__ deg,
    const int* __restrict__ csr, const float* __restrict__ dinv,
    u16* __restrict__ h1, int n_s, int n_t)
{
  int w    = (blockIdx.x * 256 + threadIdx.x) >> 6;
  int lane = threadIdx.x & 63;
  if (w >= n_t) return;
  const int g = lane >> 4;
  const int c = lane & 15;
  int start = off[w];
  int n     = deg[w];

  float r[8], p[8];
  #pragma unroll
  for (int q = 0; q < 8; q++){ r[q] = 0.f; p[q] = 0.f; }

  int i = 0;
  for (; i + 8 <= n; i += 8){
    int sa = csr[start + i + g];
    int sb = csr[start + i + 4 + g];
    int4 da = *(const int4*)(h1 + (size_t)sa * D_H + c * 8);
    int4 db = *(const int4*)(h1 + (size_t)sb * D_H + c * 8);
    const u16* ha = (const u16*)&da;
    const u16* hb = (const u16*)&db;
    #pragma unroll
    for (int q = 0; q < 8; q++){
      float va = bf2f(ha[q]), vb = bf2f(hb[q]);
      r[q] += va + vb;
      p[q] += fmaxf(va, 0.f) + fmaxf(vb, 0.f);
    }
  }
  for (; i < n; i += 4){
    if (i + g < n){
      int sa = csr[start + i + g];
      int4 da = *(const int4*)(h1 + (size_t)sa * D_H + c * 8);
      const u16* ha = (const u16*)&da;
      #pragma unroll
      for (int q = 0; q < 8; q++){
        float va = bf2f(ha[q]);
        r[q] += va;
        p[q] += fmaxf(va, 0.f);
      }
    }
  }

  #pragma unroll
  for (int q = 0; q < 8; q++){
    r[q] += __shfl_xor(r[q], 16, 64);
    r[q] += __shfl_xor(r[q], 32, 64);
    p[q] += __shfl_xor(p[q], 16, 64);
    p[q] += __shfl_xor(p[q], 32, 64);
  }

  if (g == 0){
    float di  = dinv[w];
    float di2 = di * di;
    u16* selfp = h1 + (size_t)(n_s + w) * D_H + c * 8;
    int4 hs = *(const int4*)selfp;
    const u16* hh = (const u16*)&hs;
    u16 ob[8];
    #pragma unroll
    for (int q = 0; q < 8; q++){
      float zq = fmaxf(di * r[q] + di2 * bf2f(hh[q]), 0.f);
      float uq = di * p[q] + di2 * zq;
      ob[q] = f2bf(uq);
    }
    *(int4*)selfp = *(int4*)ob;
  }
}

// ---------------- GEMM2 (MFMA, BM=128, sw-pipelined): A @ W1t -> d_out f32 ----------------
// A row r<n_s: relu on load; r>=n_s: raw u_t.
__global__ __launch_bounds__(256) void k_gemm2(
    const u16* __restrict__ h1, const u16* __restrict__ W1t,
    int M, int n_s, float* __restrict__ out)
{
  __shared__ u16 As[128 * LSTR];
  __shared__ u16 Bs[64 * LSTR];
  const int t    = threadIdx.x;
  const int wave = t >> 6, lane = t & 63;
  const int wm   = wave * 32;
  const int lm   = lane & 15, quad = lane >> 4;
  const int row0 = blockIdx.x * 128;

  f32x4 acc[2][4];
  const f32x4 z = {0.f, 0.f, 0.f, 0.f};
  #pragma unroll
  for (int i = 0; i < 2; i++)
    #pragma unroll
    for (int j = 0; j < 4; j++) acc[i][j] = z;

  const int ar = t >> 1;
  const int kh = (t & 1) * 32;
  const int r  = row0 + ar;
  const bool relu_a = (r < n_s);
  const int bn = t >> 2;
  const int bk = (t & 3) * 16;

  int4 a4[4], w4[2];
  if (r < M){
    const u16* hp = h1 + (size_t)r * D_H + kh;
    #pragma unroll
    for (int j = 0; j < 4; j++) a4[j] = *(const int4*)(hp + j * 8);
  } else {
    int4 zz = make_int4(0,0,0,0);
    #pragma unroll
    for (int j = 0; j < 4; j++) a4[j] = zz;
  }
  w4[0] = *(const int4*)(W1t + (size_t)bn * D_H + bk);
  w4[1] = *(const int4*)(W1t + (size_t)bn * D_H + bk + 8);

  for (int k0 = 0; k0 < D_H; k0 += 64){
    __syncthreads();
    {
      u16 abuf[32];
      #pragma unroll
      for (int j = 0; j < 4; j++){
        u16* hh = (u16*)&a4[j];
        #pragma unroll
        for (int q = 0; q < 8; q++){
          u16 v = hh[q];
          abuf[j*8+q] = (relu_a && (v & 0x8000u)) ? (u16)0 : v;
        }
      }
      u16* ap = &As[ar * LSTR + kh];
      *(int4*)(ap +  0) = *(int4*)&abuf[0];
      *(int4*)(ap +  8) = *(int4*)&abuf[8];
      *(int4*)(ap + 16) = *(int4*)&abuf[16];
      *(int4*)(ap + 24) = *(int4*)&abuf[24];
      u16* bp = &Bs[bn * LSTR + bk];
      *(int4*)(bp + 0) = w4[0];
      *(int4*)(bp + 8) = w4[1];
    }
    __syncthreads();

    if (k0 + 64 < D_H){
      if (r < M){
        const u16* hp = h1 + (size_t)r * D_H + k0 + 64 + kh;
        #pragma unroll
        for (int j = 0; j < 4; j++) a4[j] = *(const int4*)(hp + j * 8);
      }
      w4[0] = *(const int4*)(W1t + (size_t)bn * D_H + k0 + 64 + bk);
      w4[1] = *(const int4*)(W1t + (size_t)bn * D_H + k0 + 64 + bk + 8);
    }

    #pragma unroll
    for (int kk = 0; kk < 64; kk += 32){
      bf16x8 af[2], bfr[4];
      #pragma unroll
      for (int i = 0; i < 2; i++)
        af[i] = *(const bf16x8*)&As[(wm + i*16 + lm) * LSTR + kk + quad*8];
      #pragma unroll
      for (int i = 0; i < 4; i++)
        bfr[i] = *(const bf16x8*)&Bs[(i*16 + lm) * LSTR + kk + quad*8];
      #pragma unroll
      for (int mi = 0; mi < 2; mi++)
        #pragma unroll
        for (int ni = 0; ni < 4; ni++)
          acc[mi][ni] = __builtin_amdgcn_mfma_f32_16x16x32_bf16(
              af[mi], bfr[ni], acc[mi][ni], 0, 0, 0);
    }
  }

  #pragma unroll
  for (int mi = 0; mi < 2; mi++){
    int rbase = row0 + wm + mi * 16 + quad * 4;
    #pragma unroll
    for (int rr = 0; rr < 4; rr++){
      int m = rbase + rr;
      if (m >= M) continue;
      float* op = out + (size_t)m * D_OUT + lm;
      #pragma unroll
      for (int ni = 0; ni < 4; ni++)
        op[ni * 16] = acc[mi][ni][rr];
    }
  }
}

static inline size_t alup(size_t x){ return (x + 255) & ~(size_t)255; }

extern "C" void kernel_launch(void* const* d_in, const int* in_sizes, int n_in,
                              void* d_out, int out_size, void* d_ws, size_t ws_size,
                              hipStream_t stream)
{
  const int*   ei = (const int*)d_in[0];
  const float* xs = (const float*)d_in[1];
  const float* xt = (const float*)d_in[2];
  const float* W0 = (const float*)d_in[3];
  const float* W1 = (const float*)d_in[4];
  const int E   = in_sizes[0] / 2;
  const int n_s = in_sizes[1] / D_IN;
  const int n_t = in_sizes[2] / D_IN;
  const int M   = n_s + n_t;
  const int* src = ei;       // edge_index row 0
  const int* dst = ei + E;   // edge_index row 1 (0-based target index)
  const int nb_t = (n_t + 255) / 256;

  // workspace layout (~29 MB)
  char* p = (char*)d_ws;
  int*   deg    = (int*)p;    p += alup((size_t)n_t * 4);
  int*   off    = (int*)p;    p += alup((size_t)n_t * 4);
  int*   cursor = (int*)p;    p += alup((size_t)n_t * 4);
  float* dinv   = (float*)p;  p += alup((size_t)n_t * 4);
  int*   bsum   = (int*)p;    p += alup((size_t)nb_t * 4);
  int*   csr    = (int*)p;    p += alup((size_t)E * 4);
  u16*   W0t    = (u16*)p;    p += alup((size_t)D_H * D_IN * 2);
  u16*   W1t    = (u16*)p;    p += alup((size_t)D_OUT * D_H * 2);
  u16*   h1     = (u16*)p;    p += alup((size_t)M * D_H * 2);

  const int wprep_n = 128*256 + 64*128 + n_t;
  k_wprep <<<(wprep_n + 255) / 256, 256, 0, stream>>>(W0, W1, W0t, W1t, deg, n_t);
  k_deg   <<<(E + 255) / 256, 256, 0, stream>>>(dst, E, deg);
  k_bsum  <<<nb_t, 256, 0, stream>>>(deg, n_t, bsum);
  k_off   <<<nb_t, 256, 0, stream>>>(deg, n_t, bsum, nb_t, off, cursor, dinv);
  k_fill  <<<(E + 255) / 256, 256, 0, stream>>>(src, dst, E, cursor, csr);

  // layer 1: h1 = X @ W0 (raw, all rows, bf16)
  k_gemm1<<<(M + 127) / 128, 256, 0, stream>>>(xs, xt, W0t, M, n_s, h1);
  // fused agg: h1 target rows <- u_t (single gather pass for both layers)
  k_aggf <<<(n_t + 3) / 4, 256, 0, stream>>>(off, deg, csr, dinv, h1, n_s, n_t);
  // layer 2: d_out = [relu(h1_s); u_t] @ W1  (final output)
  k_gemm2<<<(M + 127) / 128, 256, 0, stream>>>(h1, W1t, M, n_s, (float*)d_out);
}